// Round 2
// baseline (351.331 us; speedup 1.0000x reference)
//
#include <hip/hip_runtime.h>
#include <stdint.h>

#define B_ 4
#define S_ 1024
#define D_ 512
#define H_ 8
#define DH_ 64
#define INNER_ 1536
#define M_ (B_*S_)   // 4096

typedef unsigned short u16;
typedef __attribute__((ext_vector_type(8))) short sh8;      // 8 bf16 in 4 VGPRs
typedef __attribute__((ext_vector_type(4))) float f32x4;

__device__ __forceinline__ float bf2f(u16 u) {
  union { unsigned int i; float f; } v; v.i = ((unsigned int)u) << 16; return v.f;
}
__device__ __forceinline__ u16 f2bf(float f) {
  union { float f; unsigned int i; } v; v.f = f;
  unsigned int u = v.i;
  return (u16)((u + 0x7FFFu + ((u >> 16) & 1u)) >> 16);
}

// ---------------- fp32 -> bf16 convert ----------------
__global__ __launch_bounds__(256) void f2b_kernel(const float* __restrict__ in,
                                                  u16* __restrict__ out) {
  int i = (blockIdx.x * 256 + threadIdx.x) * 4;
  float4 v = *(const float4*)(in + i);
  uint2 o;
  o.x = (unsigned int)f2bf(v.x) | ((unsigned int)f2bf(v.y) << 16);
  o.y = (unsigned int)f2bf(v.z) | ((unsigned int)f2bf(v.w) << 16);
  *(uint2*)(out + i) = o;
}

// ---------------- transpose + convert: out[n][k] = bf16(in[k][n]), in fp32 ----------------
__global__ __launch_bounds__(256) void transpose_f2b(const float* __restrict__ in,
                                                     u16* __restrict__ out,
                                                     int K, int N) {
  __shared__ u16 tile[64][65];
  int tx = threadIdx.x & 63, ty = threadIdx.x >> 6;
  int n0 = blockIdx.x * 64, k0 = blockIdx.y * 64;
  #pragma unroll
  for (int i = 0; i < 16; i++) {
    int k = ty + i * 4;
    tile[k][tx] = f2bf(in[(size_t)(k0 + k) * N + n0 + tx]);
  }
  __syncthreads();
  #pragma unroll
  for (int i = 0; i < 16; i++) {
    int n = ty + i * 4;
    out[(size_t)(n0 + n) * K + k0 + tx] = tile[tx][n];
  }
}

// ---------------- GEMM: C[M,N] = A[M,K] @ Bt[N,K]^T, bf16 in, fp32 acc ----------------
// EPI 1: qkv scatter (+bias0=bq, bias1=bkv), all biases fp32
// EPI 2: +bias0 +aux(fp32 residual) -> outF fp32
// EPI 3: plain -> outU bf16
// EPI 4: +aux(fp32 residual) -> outF fp32
template<int EPI>
__global__ __launch_bounds__(256) void gemm_bt(
    const u16* __restrict__ A, const u16* __restrict__ Bt,
    int M, int N, int K,
    const float* __restrict__ bias0, const float* __restrict__ bias1,
    const float* __restrict__ aux,
    float* __restrict__ outF, u16* __restrict__ outU,
    u16* __restrict__ qo, u16* __restrict__ ko_, u16* __restrict__ vto)
{
  __shared__ u16 As[128 * 32];
  __shared__ u16 Bs[128 * 32];
  int tid = threadIdx.x;
  int gx = blockIdx.x, gy = blockIdx.y;
  int l = tid & 63, w = tid >> 6;
  int l15 = l & 15, quad = l >> 4;
  int wm = (w >> 1) * 64, wn = (w & 1) * 64;
  f32x4 acc[4][4] = {};

  int srow = tid >> 2;          // 0..63
  int scol = (tid & 3) * 8;     // 0,8,16,24
  const u16* Ag = A  + (size_t)(gy * 128 + srow) * K + scol;
  const u16* Bg = Bt + (size_t)(gx * 128 + srow) * K + scol;

  for (int ko = 0; ko < K; ko += 32) {
    uint4 a0 = *(const uint4*)(Ag + ko);
    uint4 a1 = *(const uint4*)(Ag + (size_t)64 * K + ko);
    uint4 b0 = *(const uint4*)(Bg + ko);
    uint4 b1 = *(const uint4*)(Bg + (size_t)64 * K + ko);
    __syncthreads();
    *(uint4*)&As[srow * 32 + scol] = a0;
    *(uint4*)&As[(srow + 64) * 32 + scol] = a1;
    *(uint4*)&Bs[srow * 32 + scol] = b0;
    *(uint4*)&Bs[(srow + 64) * 32 + scol] = b1;
    __syncthreads();
    sh8 af[4], bfr[4];
    #pragma unroll
    for (int mi = 0; mi < 4; mi++)
      af[mi] = *(const sh8*)&As[(wm + mi * 16 + l15) * 32 + quad * 8];
    #pragma unroll
    for (int ni = 0; ni < 4; ni++)
      bfr[ni] = *(const sh8*)&Bs[(wn + ni * 16 + l15) * 32 + quad * 8];
    #pragma unroll
    for (int mi = 0; mi < 4; mi++)
      #pragma unroll
      for (int ni = 0; ni < 4; ni++)
        acc[mi][ni] = __builtin_amdgcn_mfma_f32_16x16x32_bf16(af[mi], bfr[ni], acc[mi][ni], 0, 0, 0);
  }

  #pragma unroll
  for (int mi = 0; mi < 4; mi++) {
    #pragma unroll
    for (int ni = 0; ni < 4; ni++) {
      #pragma unroll
      for (int r = 0; r < 4; r++) {
        int grow = gy * 128 + wm + mi * 16 + quad * 4 + r;
        int gcol = gx * 128 + wn + ni * 16 + l15;
        float v = acc[mi][ni][r];
        if (EPI == 1) {
          int b = grow >> 10, s = grow & 1023;
          if (gcol < 512) {
            int h = gcol >> 6, dh = gcol & 63;
            qo[(((size_t)b * H_ + h) * S_ + s) * DH_ + dh] = f2bf(v + bias0[gcol]);
          } else {
            int n2 = gcol - 512;
            int two = n2 >> 9, h = (n2 >> 6) & 7, dh = n2 & 63;
            float vv = v + bias1[n2];
            if (two == 0) ko_[(((size_t)b * H_ + h) * S_ + s) * DH_ + dh] = f2bf(vv);
            else          vto[(((size_t)b * H_ + h) * DH_ + dh) * S_ + s] = f2bf(vv);
          }
        } else if (EPI == 2) {
          v += bias0[gcol] + aux[(size_t)grow * N + gcol];
          outF[(size_t)grow * N + gcol] = v;
        } else if (EPI == 3) {
          outU[(size_t)grow * N + gcol] = f2bf(v);
        } else {
          v += aux[(size_t)grow * N + gcol];
          outF[(size_t)grow * N + gcol] = v;
        }
      }
    }
  }
}

// ---------------- sparse attention ----------------
__global__ __launch_bounds__(256) void attn_kernel(
    const u16* __restrict__ q, const u16* __restrict__ kk,
    const u16* __restrict__ vt, u16* __restrict__ attn)
{
  __shared__ __align__(16) char smem[16 * 1028 * 4 + 64];
  float (*sc)[1028] = (float (*)[1028])smem;
  u16 (*cb)[1032] = (u16 (*)[1032])smem;       // aliased on sc (guarded by barriers)
  float* zinv = (float*)(smem + 16 * 1028 * 4);

  int tid = threadIdx.x;
  int l = tid & 63, w = tid >> 6;
  int l15 = l & 15, quad = l >> 4;
  int blk = blockIdx.x;
  int bh = blk >> 6;             // b*8+h
  int r0 = (blk & 63) << 4;      // query tile start

  const u16* qb = q  + ((size_t)bh * S_ + r0) * DH_;
  const u16* kb = kk + (size_t)bh * S_ * DH_;
  const u16* vb = vt + (size_t)bh * DH_ * S_;

  sh8 aq0 = *(const sh8*)(qb + l15 * DH_ + quad * 8);
  sh8 aq1 = *(const sh8*)(qb + l15 * DH_ + 32 + quad * 8);

  // phase A: scores = (Q K^T) / 8 -> LDS
  #pragma unroll
  for (int i = 0; i < 16; i++) {
    int t0 = ((i << 2) | w) << 4;
    const u16* kr = kb + (size_t)(t0 + l15) * DH_;
    sh8 bk0 = *(const sh8*)(kr + quad * 8);
    sh8 bk1 = *(const sh8*)(kr + 32 + quad * 8);
    f32x4 s4 = {};
    s4 = __builtin_amdgcn_mfma_f32_16x16x32_bf16(aq0, bk0, s4, 0, 0, 0);
    s4 = __builtin_amdgcn_mfma_f32_16x16x32_bf16(aq1, bk1, s4, 0, 0, 0);
    #pragma unroll
    for (int r = 0; r < 4; r++)
      sc[quad * 4 + r][t0 + l15] = s4[r] * 0.125f;
  }
  __syncthreads();

  // phase B: per-row softmax + top-512 threshold + coefficients, in registers
  int row = tid >> 4, l16 = tid & 15;
  float wv[64];
  #pragma unroll
  for (int j = 0; j < 64; j++) wv[j] = sc[row][l16 + (j << 4)];

  float mx = wv[0];
  #pragma unroll
  for (int j = 1; j < 64; j++) mx = fmaxf(mx, wv[j]);
  #pragma unroll
  for (int d = 1; d < 16; d <<= 1) mx = fmaxf(mx, __shfl_xor(mx, d));

  float sum = 0.f;
  #pragma unroll
  for (int j = 0; j < 64; j++) { wv[j] = __expf(wv[j] - mx); sum += wv[j]; }
  #pragma unroll
  for (int d = 1; d < 16; d <<= 1) sum += __shfl_xor(sum, d);
  float invZ = 1.0f / sum;
  #pragma unroll
  for (int j = 0; j < 64; j++) wv[j] *= invZ;

  // binary search on fp32 bit pattern (all w >= 0): largest T with count(w>=T) >= 512
  unsigned int lo = 0u;
  bool done = false;
  for (int bit = 29; bit >= 0; bit--) {
    unsigned int cand = lo | (1u << bit);
    float T = __uint_as_float(cand);
    int cnt = 0;
    #pragma unroll
    for (int j = 0; j < 64; j++) cnt += (wv[j] >= T) ? 1 : 0;
    #pragma unroll
    for (int d = 1; d < 16; d <<= 1) cnt += __shfl_xor(cnt, d);
    if (cnt >= 512) lo = cand;
    done = done || (cnt == 512);
    if (__all(done)) break;
  }
  float T = __uint_as_float(lo);

  float Z2 = 0.f;
  #pragma unroll
  for (int j = 0; j < 64; j++) {
    float c = (wv[j] >= T) ? __expf(wv[j]) : 1.0f;   // exp(0)=1 for masked slots
    Z2 += c; wv[j] = c;
  }
  #pragma unroll
  for (int d = 1; d < 16; d <<= 1) Z2 += __shfl_xor(Z2, d);

  __syncthreads();   // all sc reads complete before aliased cb writes
  #pragma unroll
  for (int j = 0; j < 64; j++) cb[row][l16 + (j << 4)] = f2bf(wv[j]);
  if (l16 == 0) zinv[row] = 1.0f / Z2;
  __syncthreads();

  // phase E: o = (c @ V) * zinv  via MFMA, vT gives contiguous B-operand reads
  int n0 = w << 4;
  f32x4 oacc = {};
  #pragma unroll
  for (int kt = 0; kt < 32; kt++) {
    sh8 ca = *(const sh8*)&cb[l15][kt * 32 + quad * 8];
    sh8 vv = *(const sh8*)(vb + (size_t)(n0 + l15) * S_ + kt * 32 + quad * 8);
    oacc = __builtin_amdgcn_mfma_f32_16x16x32_bf16(ca, vv, oacc, 0, 0, 0);
  }
  int b = bh >> 3, h = bh & 7;
  #pragma unroll
  for (int r = 0; r < 4; r++) {
    int rr = quad * 4 + r;
    float o = oacc[r] * zinv[rr];
    attn[((size_t)b * S_ + r0 + rr) * D_ + h * DH_ + n0 + l15] = f2bf(o);
  }
}

// ---------------- RMS norm over D per row: fp32 in, bf16 + fp32 out ----------------
__global__ __launch_bounds__(128) void rms_kernel(const float* __restrict__ in,
                                                  const float* __restrict__ w,
                                                  u16* __restrict__ out,
                                                  float* __restrict__ outF) {
  int row = blockIdx.x;
  int tid = threadIdx.x;
  const float* r = in + (size_t)row * D_;
  float v0 = r[tid], v1 = r[tid + 128], v2 = r[tid + 256], v3 = r[tid + 384];
  float s = v0 * v0 + v1 * v1 + v2 * v2 + v3 * v3;
  #pragma unroll
  for (int d = 1; d < 64; d <<= 1) s += __shfl_xor(s, d);
  __shared__ float red[2];
  if ((tid & 63) == 0) red[tid >> 6] = s;
  __syncthreads();
  s = red[0] + red[1];
  float rs = rsqrtf(s * (1.0f / 512.0f) + 1e-6f);
  #pragma unroll
  for (int i = 0; i < 4; i++) {
    int d = tid + i * 128;
    float hv = (i == 0 ? v0 : i == 1 ? v1 : i == 2 ? v2 : v3) * rs * w[d];
    out [(size_t)row * D_ + d] = f2bf(hv);
    outF[(size_t)row * D_ + d] = hv;
  }
}

// ---------------- silu(a)*b (bf16 in/out) ----------------
__global__ __launch_bounds__(256) void silu_mul_kernel(const u16* __restrict__ ab,
                                                       u16* __restrict__ g) {
  size_t i = ((size_t)blockIdx.x * 256 + threadIdx.x) * 8;
  size_t m = i / INNER_, j = i % INNER_;
  const u16* pa = ab + m * (2 * INNER_) + j;
  uint4 av = *(const uint4*)pa;
  uint4 bv = *(const uint4*)(pa + INNER_);
  unsigned int aa[4] = {av.x, av.y, av.z, av.w};
  unsigned int bb[4] = {bv.x, bv.y, bv.z, bv.w};
  unsigned int rr[4];
  #pragma unroll
  for (int t = 0; t < 4; t++) {
    float a0 = bf2f((u16)(aa[t] & 0xFFFF)), a1 = bf2f((u16)(aa[t] >> 16));
    float b0 = bf2f((u16)(bb[t] & 0xFFFF)), b1 = bf2f((u16)(bb[t] >> 16));
    float c0 = a0 / (1.f + __expf(-a0)) * b0;
    float c1 = a1 / (1.f + __expf(-a1)) * b1;
    rr[t] = (unsigned int)f2bf(c0) | ((unsigned int)f2bf(c1) << 16);
  }
  uint4 o; o.x = rr[0]; o.y = rr[1]; o.z = rr[2]; o.w = rr[3];
  *(uint4*)(g + m * INNER_ + j) = o;
}

// ---------------- instance norm ----------------
__global__ void zero_kernel(float* p, int n) {
  int i = blockIdx.x * 256 + threadIdx.x;
  if (i < n) p[i] = 0.f;
}

__global__ __launch_bounds__(256) void inorm_stats(const float* __restrict__ y,
                                                   float* __restrict__ stats) {
  int b = blockIdx.x, dc = blockIdx.y, scn = blockIdx.z;
  int dl = threadIdx.x & 63, sl = threadIdx.x >> 6;
  int d = dc * 64 + dl;
  const float* yb = y + (size_t)b * S_ * D_ + d;
  float s1 = 0.f, s2 = 0.f;
  for (int i = 0; i < 32; i++) {
    int s = scn * 128 + sl * 32 + i;
    float v = yb[(size_t)s * D_];
    s1 += v; s2 += v * v;
  }
  __shared__ float r1[256], r2[256];
  r1[threadIdx.x] = s1; r2[threadIdx.x] = s2;
  __syncthreads();
  if (sl == 0) {
    s1 = r1[dl] + r1[dl + 64] + r1[dl + 128] + r1[dl + 192];
    s2 = r2[dl] + r2[dl + 64] + r2[dl + 128] + r2[dl + 192];
    atomicAdd(&stats[((size_t)b * D_ + d) * 2], s1);
    atomicAdd(&stats[((size_t)b * D_ + d) * 2 + 1], s2);
  }
}

__global__ __launch_bounds__(256) void inorm_apply(const float* __restrict__ y,
                                                   const float* __restrict__ stats,
                                                   const float* __restrict__ w,
                                                   const float* __restrict__ bias,
                                                   float* __restrict__ out) {
  int row = blockIdx.x;            // b*S + s
  int b = row >> 10;
  int tid = threadIdx.x;
  #pragma unroll
  for (int i = 0; i < 2; i++) {
    int d = tid + i * 256;
    float m  = stats[((size_t)b * D_ + d) * 2]     * (1.f / 1024.f);
    float v2 = stats[((size_t)b * D_ + d) * 2 + 1] * (1.f / 1024.f);
    float rs = rsqrtf(v2 - m * m + 1e-5f);
    float v = y[(size_t)row * D_ + d];
    out[(size_t)row * D_ + d] = (v - m) * rs * w[d] + bias[d];
  }
}

// ---------------- launch ----------------
extern "C" void kernel_launch(void* const* d_in, const int* in_sizes, int n_in,
                              void* d_out, int out_size, void* d_ws, size_t ws_size,
                              hipStream_t stream) {
  const float* x    = (const float*)d_in[0];
  const float* Wq   = (const float*)d_in[1];
  const float* bq   = (const float*)d_in[2];
  const float* Wkv  = (const float*)d_in[3];
  const float* bkv  = (const float*)d_in[4];
  const float* Wo   = (const float*)d_in[5];
  const float* bo   = (const float*)d_in[6];
  const float* rmsw = (const float*)d_in[7];
  const float* l1   = (const float*)d_in[8];
  const float* l2   = (const float*)d_in[9];
  const float* l3   = (const float*)d_in[10];
  const float* inw  = (const float*)d_in[11];
  const float* inb  = (const float*)d_in[12];
  float* out = (float*)d_out;

  char* ws = (char*)d_ws;
  size_t off = 0;
  auto alloc = [&](size_t n) { char* p = ws + off; off += (n + 255) & ~(size_t)255; return p; };
  u16*  xb   = (u16*) alloc((size_t)M_ * D_ * 2);      // x in bf16
  u16*  Wt1  = (u16*) alloc((size_t)1536 * 512 * 2);   // [Wq^T ; Wkv^T]  [1536,512]
  u16*  Wot  = (u16*) alloc((size_t)512 * 512 * 2);
  u16*  W12t = (u16*) alloc((size_t)3072 * 512 * 2);   // [l1^T ; l2^T]
  u16*  l3t  = (u16*) alloc((size_t)512 * 1536 * 2);
  u16*  qb   = (u16*) alloc((size_t)M_ * D_ * 2);      // [B,H,S,DH]
  u16*  kb   = (u16*) alloc((size_t)M_ * D_ * 2);      // [B,H,S,DH]
  u16*  vtb  = (u16*) alloc((size_t)M_ * D_ * 2);      // [B,H,DH,S]
  u16*  attn = (u16*) alloc((size_t)M_ * D_ * 2);      // [B,S,D]
  float* tmpF = (float*)alloc((size_t)M_ * D_ * 4);    // G2 out, then y (G4 out)
  u16*  hhat = (u16*) alloc((size_t)M_ * D_ * 2);
  float* hhatF = (float*)alloc((size_t)M_ * D_ * 4);
  u16*  ab   = (u16*) alloc((size_t)M_ * 3072 * 2);
  u16*  g    = (u16*) alloc((size_t)M_ * INNER_ * 2);
  float* stats = (float*)alloc((size_t)B_ * D_ * 2 * 4);

  // x -> bf16
  f2b_kernel<<<2048, 256, 0, stream>>>(x, xb);

  // weight transposes (fp32 -> bf16)
  transpose_f2b<<<dim3(8, 8),  256, 0, stream>>>(Wq,  Wt1,               512, 512);
  transpose_f2b<<<dim3(16, 8), 256, 0, stream>>>(Wkv, Wt1 + 512 * 512,   512, 1024);
  transpose_f2b<<<dim3(8, 8),  256, 0, stream>>>(Wo,  Wot,               512, 512);
  transpose_f2b<<<dim3(24, 8), 256, 0, stream>>>(l1,  W12t,              512, 1536);
  transpose_f2b<<<dim3(24, 8), 256, 0, stream>>>(l2,  W12t + 1536 * 512, 512, 1536);
  transpose_f2b<<<dim3(8, 24), 256, 0, stream>>>(l3,  l3t,               1536, 512);

  // QKV projection with scatter epilogue
  gemm_bt<1><<<dim3(12, 32), 256, 0, stream>>>(xb, Wt1, M_, 1536, 512,
      bq, bkv, nullptr, nullptr, nullptr, qb, kb, vtb);

  // sparse attention
  attn_kernel<<<2048, 256, 0, stream>>>(qb, kb, vtb, attn);

  // out proj + bias + residual(x fp32) -> fp32
  gemm_bt<2><<<dim3(4, 32), 256, 0, stream>>>(attn, Wot, M_, 512, 512,
      bo, nullptr, x, tmpF, nullptr, nullptr, nullptr, nullptr);

  // RMS norm -> h_hat bf16 + fp32
  rms_kernel<<<4096, 128, 0, stream>>>(tmpF, rmsw, hhat, hhatF);

  // FFN up (l1|l2)
  gemm_bt<3><<<dim3(24, 32), 256, 0, stream>>>(hhat, W12t, M_, 3072, 512,
      nullptr, nullptr, nullptr, nullptr, ab, nullptr, nullptr, nullptr);

  // silu(a)*b
  silu_mul_kernel<<<3072, 256, 0, stream>>>(ab, g);

  // FFN down + residual(h_hat fp32) -> y fp32 (reuse tmpF)
  gemm_bt<4><<<dim3(4, 32), 256, 0, stream>>>(g, l3t, M_, 512, 1536,
      nullptr, nullptr, hhatF, tmpF, nullptr, nullptr, nullptr, nullptr);

  // instance norm over sequence dim
  zero_kernel<<<16, 256, 0, stream>>>(stats, B_ * D_ * 2);
  inorm_stats<<<dim3(4, 8, 8), 256, 0, stream>>>(tmpF, stats);
  inorm_apply<<<4096, 256, 0, stream>>>(tmpF, stats, inw, inb, out);
}

// Round 3
// 307.715 us; speedup vs baseline: 1.1417x; 1.1417x over previous
//
#include <hip/hip_runtime.h>
#include <stdint.h>

#define B_ 4
#define S_ 1024
#define D_ 512
#define H_ 8
#define DH_ 64
#define INNER_ 1536
#define M_ (B_*S_)   // 4096

typedef unsigned short u16;
typedef __attribute__((ext_vector_type(8))) short sh8;      // 8 bf16
typedef __attribute__((ext_vector_type(8))) _Float16 h8;    // 8 f16
typedef __attribute__((ext_vector_type(4))) _Float16 h4;    // 4 f16
typedef __attribute__((ext_vector_type(4))) float f32x4;

__device__ __forceinline__ float bf2f(u16 u) {
  union { unsigned int i; float f; } v; v.i = ((unsigned int)u) << 16; return v.f;
}
__device__ __forceinline__ u16 f2bf(float f) {
  union { float f; unsigned int i; } v; v.f = f;
  unsigned int u = v.i;
  return (u16)((u + 0x7FFFu + ((u >> 16) & 1u)) >> 16);
}
__device__ __forceinline__ u16 f2h(float f) {
  _Float16 h = (_Float16)f;
  return *(u16*)&h;
}

// ---------------- fp32 -> bf16 convert ----------------
__global__ __launch_bounds__(256) void f2b_kernel(const float* __restrict__ in,
                                                  u16* __restrict__ out) {
  int i = (blockIdx.x * 256 + threadIdx.x) * 4;
  float4 v = *(const float4*)(in + i);
  uint2 o;
  o.x = (unsigned int)f2bf(v.x) | ((unsigned int)f2bf(v.y) << 16);
  o.y = (unsigned int)f2bf(v.z) | ((unsigned int)f2bf(v.w) << 16);
  *(uint2*)(out + i) = o;
}

// ---------------- transpose + convert: out[n][k] = bf16(in[k][n]) ----------------
__global__ __launch_bounds__(256) void transpose_f2b(const float* __restrict__ in,
                                                     u16* __restrict__ out,
                                                     int K, int N) {
  __shared__ u16 tile[64][65];
  int tx = threadIdx.x & 63, ty = threadIdx.x >> 6;
  int n0 = blockIdx.x * 64, k0 = blockIdx.y * 64;
  #pragma unroll
  for (int i = 0; i < 16; i++) {
    int k = ty + i * 4;
    tile[k][tx] = f2bf(in[(size_t)(k0 + k) * N + n0 + tx]);
  }
  __syncthreads();
  #pragma unroll
  for (int i = 0; i < 16; i++) {
    int n = ty + i * 4;
    out[(size_t)(n0 + n) * K + k0 + tx] = tile[tx][n];
  }
}

// ---------------- GEMM: C[M,N] = A[M,K] @ Bt[N,K]^T, bf16 in, fp32 acc ----------------
// EPI 1: qkv scatter (+biases), q/k/v stored as f16
// EPI 2: +bias0 +aux(fp32 residual) -> outF fp32
// EPI 3: plain -> outU bf16
// EPI 4: +aux(fp32 residual) -> outF fp32
template<int EPI>
__global__ __launch_bounds__(256) void gemm_bt(
    const u16* __restrict__ A, const u16* __restrict__ Bt,
    int M, int N, int K,
    const float* __restrict__ bias0, const float* __restrict__ bias1,
    const float* __restrict__ aux,
    float* __restrict__ outF, u16* __restrict__ outU,
    u16* __restrict__ qo, u16* __restrict__ ko_, u16* __restrict__ vto)
{
  __shared__ u16 As[128 * 32];
  __shared__ u16 Bs[128 * 32];
  int tid = threadIdx.x;
  int gx = blockIdx.x, gy = blockIdx.y;
  int l = tid & 63, w = tid >> 6;
  int l15 = l & 15, quad = l >> 4;
  int wm = (w >> 1) * 64, wn = (w & 1) * 64;
  f32x4 acc[4][4] = {};

  int srow = tid >> 2;
  int scol = (tid & 3) * 8;
  const u16* Ag = A  + (size_t)(gy * 128 + srow) * K + scol;
  const u16* Bg = Bt + (size_t)(gx * 128 + srow) * K + scol;

  for (int ko = 0; ko < K; ko += 32) {
    uint4 a0 = *(const uint4*)(Ag + ko);
    uint4 a1 = *(const uint4*)(Ag + (size_t)64 * K + ko);
    uint4 b0 = *(const uint4*)(Bg + ko);
    uint4 b1 = *(const uint4*)(Bg + (size_t)64 * K + ko);
    __syncthreads();
    *(uint4*)&As[srow * 32 + scol] = a0;
    *(uint4*)&As[(srow + 64) * 32 + scol] = a1;
    *(uint4*)&Bs[srow * 32 + scol] = b0;
    *(uint4*)&Bs[(srow + 64) * 32 + scol] = b1;
    __syncthreads();
    sh8 af[4], bfr[4];
    #pragma unroll
    for (int mi = 0; mi < 4; mi++)
      af[mi] = *(const sh8*)&As[(wm + mi * 16 + l15) * 32 + quad * 8];
    #pragma unroll
    for (int ni = 0; ni < 4; ni++)
      bfr[ni] = *(const sh8*)&Bs[(wn + ni * 16 + l15) * 32 + quad * 8];
    #pragma unroll
    for (int mi = 0; mi < 4; mi++)
      #pragma unroll
      for (int ni = 0; ni < 4; ni++)
        acc[mi][ni] = __builtin_amdgcn_mfma_f32_16x16x32_bf16(af[mi], bfr[ni], acc[mi][ni], 0, 0, 0);
  }

  #pragma unroll
  for (int mi = 0; mi < 4; mi++) {
    #pragma unroll
    for (int ni = 0; ni < 4; ni++) {
      #pragma unroll
      for (int r = 0; r < 4; r++) {
        int grow = gy * 128 + wm + mi * 16 + quad * 4 + r;
        int gcol = gx * 128 + wn + ni * 16 + l15;
        float v = acc[mi][ni][r];
        if (EPI == 1) {
          int b = grow >> 10, s = grow & 1023;
          if (gcol < 512) {
            int h = gcol >> 6, dh = gcol & 63;
            qo[(((size_t)b * H_ + h) * S_ + s) * DH_ + dh] = f2h(v + bias0[gcol]);
          } else {
            int n2 = gcol - 512;
            int two = n2 >> 9, h = (n2 >> 6) & 7, dh = n2 & 63;
            float vv = v + bias1[n2];
            if (two == 0) ko_[(((size_t)b * H_ + h) * S_ + s) * DH_ + dh] = f2h(vv);
            else          vto[(((size_t)b * H_ + h) * DH_ + dh) * S_ + s] = f2h(vv);
          }
        } else if (EPI == 2) {
          v += bias0[gcol] + aux[(size_t)grow * N + gcol];
          outF[(size_t)grow * N + gcol] = v;
        } else if (EPI == 3) {
          outU[(size_t)grow * N + gcol] = f2bf(v);
        } else {
          v += aux[(size_t)grow * N + gcol];
          outF[(size_t)grow * N + gcol] = v;
        }
      }
    }
  }
}

// ---------------- sparse attention (f16 path, histogram top-k) ----------------
__global__ __launch_bounds__(256, 4) void attn_kernel(
    const u16* __restrict__ q, const u16* __restrict__ kk,
    const u16* __restrict__ vt, u16* __restrict__ attn)
{
  // union region: sc/cb rows (u16, stride 1028 u16 = 2056B, 16 rows = 32.9KB)
  //               hist (u32, stride 520 u32, 16 rows = 33.3KB)
  __shared__ __align__(16) char smem[33344];
  u16* scb = (u16*)smem;
  uint32_t* hist = (uint32_t*)smem;
  float* zinv = (float*)(smem + 33280);

  int tid = threadIdx.x;
  int l = tid & 63, w = tid >> 6;
  int l15 = l & 15, quad = l >> 4;
  int blk = blockIdx.x;
  int bh = blk >> 6;             // b*8+h
  int r0 = (blk & 63) << 4;      // query tile start

  const u16* qb = q  + ((size_t)bh * S_ + r0) * DH_;
  const u16* kb = kk + (size_t)bh * S_ * DH_;
  const u16* vb = vt + (size_t)bh * DH_ * S_;

  h8 aq0 = *(const h8*)(qb + l15 * DH_ + quad * 8);
  h8 aq1 = *(const h8*)(qb + l15 * DH_ + 32 + quad * 8);

  // ---- phase A: scores = (K Q^T)/8 -> LDS f16. Operand swap: D[t][qrow],
  // so each lane owns 4 consecutive t for one query row -> b64 stores.
  #pragma unroll
  for (int i = 0; i < 16; i++) {
    int t0 = ((i << 2) | w) << 4;
    const u16* kr = kb + (size_t)(t0 + l15) * DH_;
    h8 bk0 = *(const h8*)(kr + quad * 8);
    h8 bk1 = *(const h8*)(kr + 32 + quad * 8);
    f32x4 s4 = {};
    s4 = __builtin_amdgcn_mfma_f32_16x16x32_f16(bk0, aq0, s4, 0, 0, 0);
    s4 = __builtin_amdgcn_mfma_f32_16x16x32_f16(bk1, aq1, s4, 0, 0, 0);
    h4 hv;
    #pragma unroll
    for (int r = 0; r < 4; r++) hv[r] = (_Float16)(s4[r] * 0.125f);
    // qrow = l15, t-cols = t0 + quad*4 .. +3
    *(h4*)(scb + (size_t)l15 * 1028 + t0 + quad * 4) = hv;
  }
  __syncthreads();   // B1

  // ---- phase B: per-row softmax + top-512 threshold via 2-level histogram
  int row = tid >> 4, l16 = tid & 15;     // rows 4w..4w+3 stay inside wave w
  const u16* srow_p = scb + (size_t)row * 1028;
  uint2 raw[16];
  #pragma unroll
  for (int u = 0; u < 16; u++)
    raw[u] = *(const uint2*)(srow_p + 4 * l16 + 64 * u);

  float wv[64];
  #pragma unroll
  for (int u = 0; u < 16; u++) {
    h4 hv = *(h4*)&raw[u];
    #pragma unroll
    for (int e = 0; e < 4; e++) wv[4 * u + e] = (float)hv[e];
  }
  // transform raw in place to monotone 16-bit keys (per packed half):
  // km = sign ? ~u : u|0x8000
  uint32_t* rw = (uint32_t*)raw;
  #pragma unroll
  for (int t = 0; t < 32; t++) {
    uint32_t v = rw[t], m = v & 0x80008000u;
    rw[t] = v ^ (0x80008000u | ((m >> 15) * 0x7FFFu));
  }
  __syncthreads();   // B2: sc region dead -> hist may reuse

  for (int i = tid; i < 8320; i += 256) hist[i] = 0;

  // softmax pass 1 (pure VALU, overlaps with other waves' LDS)
  float mx = wv[0];
  #pragma unroll
  for (int j = 1; j < 64; j++) mx = fmaxf(mx, wv[j]);
  #pragma unroll
  for (int d = 1; d < 16; d <<= 1) mx = fmaxf(mx, __shfl_xor(mx, d));
  float sum = 0.f;
  #pragma unroll
  for (int j = 0; j < 64; j++) { wv[j] = __expf(wv[j] - mx); sum += wv[j]; }
  #pragma unroll
  for (int d = 1; d < 16; d <<= 1) sum += __shfl_xor(sum, d);
  float invZ = 1.0f / sum;

  __syncthreads();   // B3: hist zeroed

  uint32_t* hrow = hist + row * 520;
  // coarse histogram over high byte of keys (row-local, same wave -> no barrier)
  #pragma unroll
  for (int t = 0; t < 32; t++) {
    uint32_t kp = rw[t];
    atomicAdd(&hrow[(kp >> 8) & 0xFF], 1u);
    atomicAdd(&hrow[kp >> 24], 1u);
  }
  // coarse suffix scan: find largest byte-bin b* with count(km >= b*<<8) >= 512
  uint32_t h[16];
  #pragma unroll
  for (int i = 0; i < 16; i++) h[i] = hrow[l16 * 16 + i];
  uint32_t tot = 0;
  #pragma unroll
  for (int i = 0; i < 16; i++) tot += h[i];
  uint32_t incl = tot;
  #pragma unroll
  for (int d = 1; d < 16; d <<= 1) {
    uint32_t v = __shfl_down(incl, d, 16);
    if (l16 + d < 16) incl += v;
  }
  uint32_t above_l = incl - tot;      // keys in bins owned by higher lanes
  int cand = -1; uint32_t run = 0;
  #pragma unroll
  for (int i = 15; i >= 0; i--) {
    run += h[i];
    if (cand < 0 && above_l + run >= 512u) cand = i;
  }
  int candg = (cand >= 0) ? l16 * 16 + cand : -1;
  #pragma unroll
  for (int d = 1; d < 16; d <<= 1) candg = max(candg, __shfl_xor(candg, d));
  uint32_t bstar = (uint32_t)candg;
  // count strictly above bin b*
  uint32_t ab = 0;
  #pragma unroll
  for (int i = 0; i < 16; i++) ab += ((uint32_t)(l16 * 16 + i) > bstar) ? h[i] : 0;
  #pragma unroll
  for (int d = 1; d < 16; d <<= 1) ab += __shfl_xor(ab, d);
  uint32_t need = 512u - ab;

  // fine histogram over low byte, restricted to bin b*
  #pragma unroll
  for (int t = 0; t < 32; t++) {
    uint32_t kp = rw[t];
    if (((kp >> 8) & 0xFF) == bstar) atomicAdd(&hrow[256 + (kp & 0xFF)], 1u);
    if ((kp >> 24) == bstar)         atomicAdd(&hrow[256 + ((kp >> 16) & 0xFF)], 1u);
  }
  #pragma unroll
  for (int i = 0; i < 16; i++) h[i] = hrow[256 + l16 * 16 + i];
  tot = 0;
  #pragma unroll
  for (int i = 0; i < 16; i++) tot += h[i];
  incl = tot;
  #pragma unroll
  for (int d = 1; d < 16; d <<= 1) {
    uint32_t v = __shfl_down(incl, d, 16);
    if (l16 + d < 16) incl += v;
  }
  above_l = incl - tot;
  cand = -1; run = 0;
  #pragma unroll
  for (int i = 15; i >= 0; i--) {
    run += h[i];
    if (cand < 0 && above_l + run >= need) cand = i;
  }
  candg = (cand >= 0) ? l16 * 16 + cand : -1;
  #pragma unroll
  for (int d = 1; d < 16; d <<= 1) candg = max(candg, __shfl_xor(candg, d));
  uint32_t T = (bstar << 8) | (uint32_t)candg;

  // second-softmax coefficients: c = kept ? exp(w) : exp(0)=1
  float Z2 = 0.f;
  #pragma unroll
  for (int j = 0; j < 64; j++) {
    uint32_t word = rw[j >> 1];
    uint32_t km = (j & 1) ? (word >> 16) : (word & 0xFFFFu);
    float c = (km >= T) ? __expf(wv[j] * invZ) : 1.0f;
    Z2 += c; wv[j] = c;
  }
  #pragma unroll
  for (int d = 1; d < 16; d <<= 1) Z2 += __shfl_xor(Z2, d);

  __syncthreads();   // B4: all hist reads done -> cb may overwrite region

  u16* crow_p = scb + (size_t)row * 1028;
  #pragma unroll
  for (int u = 0; u < 16; u++) {
    h4 cv;
    #pragma unroll
    for (int e = 0; e < 4; e++) cv[e] = (_Float16)wv[4 * u + e];
    *(h4*)(crow_p + 4 * l16 + 64 * u) = cv;
  }
  if (l16 == 0) zinv[row] = 1.0f / Z2;
  __syncthreads();   // B5

  // ---- phase E: o = (c @ V) * zinv via f16 MFMA
  int n0 = w << 4;
  const u16* cb_row = scb + (size_t)l15 * 1028;
  f32x4 oacc = {};
  #pragma unroll
  for (int kt = 0; kt < 32; kt++) {
    uint2 c0 = *(const uint2*)(cb_row + kt * 32 + quad * 8);
    uint2 c1 = *(const uint2*)(cb_row + kt * 32 + quad * 8 + 4);
    h8 ca; ((uint2*)&ca)[0] = c0; ((uint2*)&ca)[1] = c1;
    h8 vv = *(const h8*)(vb + (size_t)(n0 + l15) * S_ + kt * 32 + quad * 8);
    oacc = __builtin_amdgcn_mfma_f32_16x16x32_f16(ca, vv, oacc, 0, 0, 0);
  }
  int b = bh >> 3, hh = bh & 7;
  #pragma unroll
  for (int r = 0; r < 4; r++) {
    int rr = quad * 4 + r;
    float o = oacc[r] * zinv[rr];
    attn[((size_t)b * S_ + r0 + rr) * D_ + hh * DH_ + n0 + l15] = f2bf(o);
  }
}

// ---------------- RMS norm over D per row: fp32 in, bf16 + fp32 out ----------------
__global__ __launch_bounds__(128) void rms_kernel(const float* __restrict__ in,
                                                  const float* __restrict__ w,
                                                  u16* __restrict__ out,
                                                  float* __restrict__ outF) {
  int row = blockIdx.x;
  int tid = threadIdx.x;
  const float* r = in + (size_t)row * D_;
  float v0 = r[tid], v1 = r[tid + 128], v2 = r[tid + 256], v3 = r[tid + 384];
  float s = v0 * v0 + v1 * v1 + v2 * v2 + v3 * v3;
  #pragma unroll
  for (int d = 1; d < 64; d <<= 1) s += __shfl_xor(s, d);
  __shared__ float red[2];
  if ((tid & 63) == 0) red[tid >> 6] = s;
  __syncthreads();
  s = red[0] + red[1];
  float rs = rsqrtf(s * (1.0f / 512.0f) + 1e-6f);
  #pragma unroll
  for (int i = 0; i < 4; i++) {
    int d = tid + i * 128;
    float hv = (i == 0 ? v0 : i == 1 ? v1 : i == 2 ? v2 : v3) * rs * w[d];
    out [(size_t)row * D_ + d] = f2bf(hv);
    outF[(size_t)row * D_ + d] = hv;
  }
}

// ---------------- silu(a)*b (bf16 in/out) ----------------
__global__ __launch_bounds__(256) void silu_mul_kernel(const u16* __restrict__ ab,
                                                       u16* __restrict__ g) {
  size_t i = ((size_t)blockIdx.x * 256 + threadIdx.x) * 8;
  size_t m = i / INNER_, j = i % INNER_;
  const u16* pa = ab + m * (2 * INNER_) + j;
  uint4 av = *(const uint4*)pa;
  uint4 bv = *(const uint4*)(pa + INNER_);
  unsigned int aa[4] = {av.x, av.y, av.z, av.w};
  unsigned int bb[4] = {bv.x, bv.y, bv.z, bv.w};
  unsigned int rr[4];
  #pragma unroll
  for (int t = 0; t < 4; t++) {
    float a0 = bf2f((u16)(aa[t] & 0xFFFF)), a1 = bf2f((u16)(aa[t] >> 16));
    float b0 = bf2f((u16)(bb[t] & 0xFFFF)), b1 = bf2f((u16)(bb[t] >> 16));
    float c0 = a0 / (1.f + __expf(-a0)) * b0;
    float c1 = a1 / (1.f + __expf(-a1)) * b1;
    rr[t] = (unsigned int)f2bf(c0) | ((unsigned int)f2bf(c1) << 16);
  }
  uint4 o; o.x = rr[0]; o.y = rr[1]; o.z = rr[2]; o.w = rr[3];
  *(uint4*)(g + m * INNER_ + j) = o;
}

// ---------------- instance norm ----------------
__global__ void zero_kernel(float* p, int n) {
  int i = blockIdx.x * 256 + threadIdx.x;
  if (i < n) p[i] = 0.f;
}

__global__ __launch_bounds__(256) void inorm_stats(const float* __restrict__ y,
                                                   float* __restrict__ stats) {
  int b = blockIdx.x, dc = blockIdx.y, scn = blockIdx.z;
  int dl = threadIdx.x & 63, sl = threadIdx.x >> 6;
  int d = dc * 64 + dl;
  const float* yb = y + (size_t)b * S_ * D_ + d;
  float s1 = 0.f, s2 = 0.f;
  for (int i = 0; i < 32; i++) {
    int s = scn * 128 + sl * 32 + i;
    float v = yb[(size_t)s * D_];
    s1 += v; s2 += v * v;
  }
  __shared__ float r1[256], r2[256];
  r1[threadIdx.x] = s1; r2[threadIdx.x] = s2;
  __syncthreads();
  if (sl == 0) {
    s1 = r1[dl] + r1[dl + 64] + r1[dl + 128] + r1[dl + 192];
    s2 = r2[dl] + r2[dl + 64] + r2[dl + 128] + r2[dl + 192];
    atomicAdd(&stats[((size_t)b * D_ + d) * 2], s1);
    atomicAdd(&stats[((size_t)b * D_ + d) * 2 + 1], s2);
  }
}

__global__ __launch_bounds__(256) void inorm_apply(const float* __restrict__ y,
                                                   const float* __restrict__ stats,
                                                   const float* __restrict__ w,
                                                   const float* __restrict__ bias,
                                                   float* __restrict__ out) {
  int row = blockIdx.x;
  int b = row >> 10;
  int tid = threadIdx.x;
  #pragma unroll
  for (int i = 0; i < 2; i++) {
    int d = tid + i * 256;
    float m  = stats[((size_t)b * D_ + d) * 2]     * (1.f / 1024.f);
    float v2 = stats[((size_t)b * D_ + d) * 2 + 1] * (1.f / 1024.f);
    float rs = rsqrtf(v2 - m * m + 1e-5f);
    float v = y[(size_t)row * D_ + d];
    out[(size_t)row * D_ + d] = (v - m) * rs * w[d] + bias[d];
  }
}

// ---------------- launch ----------------
extern "C" void kernel_launch(void* const* d_in, const int* in_sizes, int n_in,
                              void* d_out, int out_size, void* d_ws, size_t ws_size,
                              hipStream_t stream) {
  const float* x    = (const float*)d_in[0];
  const float* Wq   = (const float*)d_in[1];
  const float* bq   = (const float*)d_in[2];
  const float* Wkv  = (const float*)d_in[3];
  const float* bkv  = (const float*)d_in[4];
  const float* Wo   = (const float*)d_in[5];
  const float* bo   = (const float*)d_in[6];
  const float* rmsw = (const float*)d_in[7];
  const float* l1   = (const float*)d_in[8];
  const float* l2   = (const float*)d_in[9];
  const float* l3   = (const float*)d_in[10];
  const float* inw  = (const float*)d_in[11];
  const float* inb  = (const float*)d_in[12];
  float* out = (float*)d_out;

  char* ws = (char*)d_ws;
  size_t off = 0;
  auto alloc = [&](size_t n) { char* p = ws + off; off += (n + 255) & ~(size_t)255; return p; };
  u16*  xb   = (u16*) alloc((size_t)M_ * D_ * 2);
  u16*  Wt1  = (u16*) alloc((size_t)1536 * 512 * 2);
  u16*  Wot  = (u16*) alloc((size_t)512 * 512 * 2);
  u16*  W12t = (u16*) alloc((size_t)3072 * 512 * 2);
  u16*  l3t  = (u16*) alloc((size_t)512 * 1536 * 2);
  u16*  qb   = (u16*) alloc((size_t)M_ * D_ * 2);      // f16 [B,H,S,DH]
  u16*  kb   = (u16*) alloc((size_t)M_ * D_ * 2);      // f16 [B,H,S,DH]
  u16*  vtb  = (u16*) alloc((size_t)M_ * D_ * 2);      // f16 [B,H,DH,S]
  u16*  attn = (u16*) alloc((size_t)M_ * D_ * 2);      // bf16 [B,S,D]
  float* tmpF = (float*)alloc((size_t)M_ * D_ * 4);
  u16*  hhat = (u16*) alloc((size_t)M_ * D_ * 2);
  float* hhatF = (float*)alloc((size_t)M_ * D_ * 4);
  u16*  ab   = (u16*) alloc((size_t)M_ * 3072 * 2);
  u16*  g    = (u16*) alloc((size_t)M_ * INNER_ * 2);
  float* stats = (float*)alloc((size_t)B_ * D_ * 2 * 4);

  f2b_kernel<<<2048, 256, 0, stream>>>(x, xb);

  transpose_f2b<<<dim3(8, 8),  256, 0, stream>>>(Wq,  Wt1,               512, 512);
  transpose_f2b<<<dim3(16, 8), 256, 0, stream>>>(Wkv, Wt1 + 512 * 512,   512, 1024);
  transpose_f2b<<<dim3(8, 8),  256, 0, stream>>>(Wo,  Wot,               512, 512);
  transpose_f2b<<<dim3(24, 8), 256, 0, stream>>>(l1,  W12t,              512, 1536);
  transpose_f2b<<<dim3(24, 8), 256, 0, stream>>>(l2,  W12t + 1536 * 512, 512, 1536);
  transpose_f2b<<<dim3(8, 24), 256, 0, stream>>>(l3,  l3t,               1536, 512);

  gemm_bt<1><<<dim3(12, 32), 256, 0, stream>>>(xb, Wt1, M_, 1536, 512,
      bq, bkv, nullptr, nullptr, nullptr, qb, kb, vtb);

  attn_kernel<<<2048, 256, 0, stream>>>(qb, kb, vtb, attn);

  gemm_bt<2><<<dim3(4, 32), 256, 0, stream>>>(attn, Wot, M_, 512, 512,
      bo, nullptr, x, tmpF, nullptr, nullptr, nullptr, nullptr);

  rms_kernel<<<4096, 128, 0, stream>>>(tmpF, rmsw, hhat, hhatF);

  gemm_bt<3><<<dim3(24, 32), 256, 0, stream>>>(hhat, W12t, M_, 3072, 512,
      nullptr, nullptr, nullptr, nullptr, ab, nullptr, nullptr, nullptr);

  silu_mul_kernel<<<3072, 256, 0, stream>>>(ab, g);

  gemm_bt<4><<<dim3(4, 32), 256, 0, stream>>>(g, l3t, M_, 512, 1536,
      nullptr, nullptr, hhatF, tmpF, nullptr, nullptr, nullptr, nullptr);

  zero_kernel<<<16, 256, 0, stream>>>(stats, B_ * D_ * 2);
  inorm_stats<<<dim3(4, 8, 8), 256, 0, stream>>>(tmpF, stats);
  inorm_apply<<<4096, 256, 0, stream>>>(tmpF, stats, inw, inb, out);
}

// Round 4
// 268.197 us; speedup vs baseline: 1.3100x; 1.1473x over previous
//
#include <hip/hip_runtime.h>
#include <stdint.h>

#define B_ 4
#define S_ 1024
#define D_ 512
#define H_ 8
#define DH_ 64
#define INNER_ 1536
#define M_ (B_*S_)   // 4096

typedef unsigned short u16;
typedef __attribute__((ext_vector_type(8))) short sh8;      // 8 bf16
typedef __attribute__((ext_vector_type(8))) _Float16 h8;    // 8 f16
typedef __attribute__((ext_vector_type(4))) _Float16 h4;    // 4 f16
typedef __attribute__((ext_vector_type(4))) float f32x4;

typedef __attribute__((address_space(1))) const void cgv;
typedef __attribute__((address_space(3))) void lv;
__device__ __forceinline__ void gl_lds16(const void* g, void* l) {
  __builtin_amdgcn_global_load_lds((cgv*)g, (lv*)l, 16, 0, 0);
}

__device__ __forceinline__ float bf2f(u16 u) {
  union { unsigned int i; float f; } v; v.i = ((unsigned int)u) << 16; return v.f;
}
__device__ __forceinline__ u16 f2bf(float f) {
  union { float f; unsigned int i; } v; v.f = f;
  unsigned int u = v.i;
  return (u16)((u + 0x7FFFu + ((u >> 16) & 1u)) >> 16);
}
__device__ __forceinline__ u16 f2h(float f) {
  _Float16 h = (_Float16)f;
  return *(u16*)&h;
}

// ---------------- fp32 -> bf16 convert ----------------
__global__ __launch_bounds__(256) void f2b_kernel(const float* __restrict__ in,
                                                  u16* __restrict__ out) {
  int i = (blockIdx.x * 256 + threadIdx.x) * 4;
  float4 v = *(const float4*)(in + i);
  uint2 o;
  o.x = (unsigned int)f2bf(v.x) | ((unsigned int)f2bf(v.y) << 16);
  o.y = (unsigned int)f2bf(v.z) | ((unsigned int)f2bf(v.w) << 16);
  *(uint2*)(out + i) = o;
}

// ---------------- all weight transposes in one launch ----------------
__global__ __launch_bounds__(256) void transpose_all(
    const float* __restrict__ Wq, const float* __restrict__ Wkv,
    const float* __restrict__ Wo, const float* __restrict__ l1,
    const float* __restrict__ l2, const float* __restrict__ l3,
    u16* __restrict__ Wt1, u16* __restrict__ Wot,
    u16* __restrict__ W12t, u16* __restrict__ l3t)
{
  int i = blockIdx.x;
  const float* in; u16* outp; int K, N, bx, by;
  if (i < 64)       { in = Wq;  outp = Wt1;              K = 512;  N = 512;           bx = i & 7;  by = i >> 3; }
  else if (i < 192) { in = Wkv; outp = Wt1 + 512 * 512;  K = 512;  N = 1024; i -= 64; bx = i & 15; by = i >> 4; }
  else if (i < 256) { in = Wo;  outp = Wot;              K = 512;  N = 512;  i -= 192; bx = i & 7;  by = i >> 3; }
  else if (i < 448) { in = l1;  outp = W12t;             K = 512;  N = 1536; i -= 256; bx = i % 24; by = i / 24; }
  else if (i < 640) { in = l2;  outp = W12t + 1536 * 512; K = 512; N = 1536; i -= 448; bx = i % 24; by = i / 24; }
  else              { in = l3;  outp = l3t;              K = 1536; N = 512;  i -= 640; bx = i & 7;  by = i >> 3; }

  __shared__ u16 tile[64][65];
  int tx = threadIdx.x & 63, ty = threadIdx.x >> 6;
  int n0 = bx * 64, k0 = by * 64;
  #pragma unroll
  for (int t = 0; t < 16; t++) {
    int k = ty + t * 4;
    tile[k][tx] = f2bf(in[(size_t)(k0 + k) * N + n0 + tx]);
  }
  __syncthreads();
  #pragma unroll
  for (int t = 0; t < 16; t++) {
    int n = ty + t * 4;
    outp[(size_t)(n0 + n) * K + k0 + tx] = tile[tx][n];
  }
}

// ---------------- 128x128 GEMM: C = A[M,K] @ Bt[N,K]^T, glds staging ----------------
// EPI 1: qkv scatter (+biases), q/k/v stored f16
// EPI 3: plain -> outU bf16
template<int EPI>
__global__ __launch_bounds__(256) void gemm_bt(
    const u16* __restrict__ A, const u16* __restrict__ Bt,
    int M, int N, int K,
    const float* __restrict__ bias0, const float* __restrict__ bias1,
    u16* __restrict__ outU,
    u16* __restrict__ qo, u16* __restrict__ ko_, u16* __restrict__ vto)
{
  __shared__ u16 As[128 * 32];
  __shared__ u16 Bs[128 * 32];
  int tid = threadIdx.x;
  int gx = blockIdx.x, gy = blockIdx.y;
  int l = tid & 63, w = tid >> 6;
  int l15 = l & 15, quad = l >> 4;
  int wm = (w >> 1) * 64, wn = (w & 1) * 64;
  f32x4 acc[4][4] = {};

  const u16* Ag = A  + (size_t)(gy * 128 + (tid >> 2)) * K + (tid & 3) * 8;
  const u16* Bg = Bt + (size_t)(gx * 128 + (tid >> 2)) * K + (tid & 3) * 8;

  for (int ko = 0; ko < K; ko += 32) {
    __syncthreads();
    gl_lds16(Ag + ko,                  &As[tid * 8]);
    gl_lds16(Ag + (size_t)64 * K + ko, &As[2048 + tid * 8]);
    gl_lds16(Bg + ko,                  &Bs[tid * 8]);
    gl_lds16(Bg + (size_t)64 * K + ko, &Bs[2048 + tid * 8]);
    __syncthreads();
    sh8 af[4], bfr[4];
    #pragma unroll
    for (int mi = 0; mi < 4; mi++)
      af[mi] = *(const sh8*)&As[(wm + mi * 16 + l15) * 32 + quad * 8];
    #pragma unroll
    for (int ni = 0; ni < 4; ni++)
      bfr[ni] = *(const sh8*)&Bs[(wn + ni * 16 + l15) * 32 + quad * 8];
    #pragma unroll
    for (int mi = 0; mi < 4; mi++)
      #pragma unroll
      for (int ni = 0; ni < 4; ni++)
        acc[mi][ni] = __builtin_amdgcn_mfma_f32_16x16x32_bf16(af[mi], bfr[ni], acc[mi][ni], 0, 0, 0);
  }

  #pragma unroll
  for (int mi = 0; mi < 4; mi++) {
    #pragma unroll
    for (int ni = 0; ni < 4; ni++) {
      #pragma unroll
      for (int r = 0; r < 4; r++) {
        int grow = gy * 128 + wm + mi * 16 + quad * 4 + r;
        int gcol = gx * 128 + wn + ni * 16 + l15;
        float v = acc[mi][ni][r];
        if (EPI == 1) {
          int b = grow >> 10, s = grow & 1023;
          if (gcol < 512) {
            int h = gcol >> 6, dh = gcol & 63;
            qo[(((size_t)b * H_ + h) * S_ + s) * DH_ + dh] = f2h(v + bias0[gcol]);
          } else {
            int n2 = gcol - 512;
            int two = n2 >> 9, h = (n2 >> 6) & 7, dh = n2 & 63;
            float vv = v + bias1[n2];
            if (two == 0) ko_[(((size_t)b * H_ + h) * S_ + s) * DH_ + dh] = f2h(vv);
            else          vto[(((size_t)b * H_ + h) * DH_ + dh) * S_ + s] = f2h(vv);
          }
        } else {
          outU[(size_t)grow * N + gcol] = f2bf(v);
        }
      }
    }
  }
}

// ---------------- 64x64 GEMM for small-N layers (512 blocks) ----------------
// EPI 2: +bias0 +auxF(fp32) -> outF ; EPI 4: +auxH(bf16) -> outF
template<int EPI>
__global__ __launch_bounds__(256) void gemm64(
    const u16* __restrict__ A, const u16* __restrict__ Bt,
    int M, int N, int K,
    const float* __restrict__ bias0, const float* __restrict__ auxF,
    const u16* __restrict__ auxH, float* __restrict__ outF)
{
  __shared__ u16 As[64 * 32];
  __shared__ u16 Bs[64 * 32];
  int tid = threadIdx.x;
  int gx = blockIdx.x, gy = blockIdx.y;
  int l = tid & 63, w = tid >> 6;
  int l15 = l & 15, quad = l >> 4;
  int wm = (w >> 1) * 32, wn = (w & 1) * 32;
  f32x4 acc[2][2] = {};

  const u16* Ag = A  + (size_t)(gy * 64 + (tid >> 2)) * K + (tid & 3) * 8;
  const u16* Bg = Bt + (size_t)(gx * 64 + (tid >> 2)) * K + (tid & 3) * 8;

  for (int ko = 0; ko < K; ko += 32) {
    __syncthreads();
    gl_lds16(Ag + ko, &As[tid * 8]);
    gl_lds16(Bg + ko, &Bs[tid * 8]);
    __syncthreads();
    sh8 af[2], bfr[2];
    #pragma unroll
    for (int mi = 0; mi < 2; mi++)
      af[mi] = *(const sh8*)&As[(wm + mi * 16 + l15) * 32 + quad * 8];
    #pragma unroll
    for (int ni = 0; ni < 2; ni++)
      bfr[ni] = *(const sh8*)&Bs[(wn + ni * 16 + l15) * 32 + quad * 8];
    #pragma unroll
    for (int mi = 0; mi < 2; mi++)
      #pragma unroll
      for (int ni = 0; ni < 2; ni++)
        acc[mi][ni] = __builtin_amdgcn_mfma_f32_16x16x32_bf16(af[mi], bfr[ni], acc[mi][ni], 0, 0, 0);
  }

  #pragma unroll
  for (int mi = 0; mi < 2; mi++) {
    #pragma unroll
    for (int ni = 0; ni < 2; ni++) {
      #pragma unroll
      for (int r = 0; r < 4; r++) {
        int grow = gy * 64 + wm + mi * 16 + quad * 4 + r;
        int gcol = gx * 64 + wn + ni * 16 + l15;
        float v = acc[mi][ni][r];
        if (EPI == 2) v += bias0[gcol] + auxF[(size_t)grow * N + gcol];
        else          v += bf2f(auxH[(size_t)grow * N + gcol]);
        outF[(size_t)grow * N + gcol] = v;
      }
    }
  }
}

// ---------------- sparse attention (register bisect top-k, no LDS atomics) ----------------
__global__ __launch_bounds__(256, 4) void attn_kernel(
    const u16* __restrict__ q, const u16* __restrict__ kk,
    const u16* __restrict__ vt, u16* __restrict__ attn)
{
  __shared__ __align__(16) char smem[16 * 1028 * 2 + 64];
  u16* scb = (u16*)smem;
  float* zinv = (float*)(smem + 16 * 1028 * 2);

  int tid = threadIdx.x;
  int l = tid & 63, w = tid >> 6;
  int l15 = l & 15, quad = l >> 4;
  int blk = blockIdx.x;
  int bh = blk >> 6;             // b*8+h
  int r0 = (blk & 63) << 4;      // query tile start

  const u16* qb = q  + ((size_t)bh * S_ + r0) * DH_;
  const u16* kb = kk + (size_t)bh * S_ * DH_;
  const u16* vb = vt + (size_t)bh * DH_ * S_;

  h8 aq0 = *(const h8*)(qb + l15 * DH_ + quad * 8);
  h8 aq1 = *(const h8*)(qb + l15 * DH_ + 32 + quad * 8);

  // ---- phase A: scores = (K Q^T)/8 -> LDS f16; operand swap -> b64 stores
  #pragma unroll
  for (int i = 0; i < 16; i++) {
    int t0 = ((i << 2) | w) << 4;
    const u16* kr = kb + (size_t)(t0 + l15) * DH_;
    h8 bk0 = *(const h8*)(kr + quad * 8);
    h8 bk1 = *(const h8*)(kr + 32 + quad * 8);
    f32x4 s4 = {};
    s4 = __builtin_amdgcn_mfma_f32_16x16x32_f16(bk0, aq0, s4, 0, 0, 0);
    s4 = __builtin_amdgcn_mfma_f32_16x16x32_f16(bk1, aq1, s4, 0, 0, 0);
    h4 hv;
    #pragma unroll
    for (int r = 0; r < 4; r++) hv[r] = (_Float16)(s4[r] * 0.125f);
    *(h4*)(scb + (size_t)l15 * 1028 + t0 + quad * 4) = hv;
  }
  __syncthreads();   // B1

  // ---- phase B: softmax + threshold bisect + coefficients, registers only
  int row = tid >> 4, l16 = tid & 15;
  const u16* srow_p = scb + (size_t)row * 1028;
  float sv[64];
  #pragma unroll
  for (int u = 0; u < 16; u++) {
    uint2 rr = *(const uint2*)(srow_p + 4 * l16 + 64 * u);
    h4 hv = *(h4*)&rr;
    #pragma unroll
    for (int e = 0; e < 4; e++) sv[4 * u + e] = (float)hv[e];
  }
  float mx = sv[0];
  #pragma unroll
  for (int j = 1; j < 64; j++) mx = fmaxf(mx, sv[j]);
  #pragma unroll
  for (int d = 1; d < 16; d <<= 1) mx = fmaxf(mx, __shfl_xor(mx, d));
  float sum = 0.f;
  #pragma unroll
  for (int j = 0; j < 64; j++) { sv[j] = __expf(sv[j] - mx); sum += sv[j]; }
  #pragma unroll
  for (int d = 1; d < 16; d <<= 1) sum += __shfl_xor(sum, d);
  float invZ = 1.0f / sum;

  // bisect threshold on e=exp(s-mx) in (0,1]: count(e>=T) ~ 512
  float lo = 0.f, hi = 1.0000001f;
  float Tsel = -1.f;
  bool done = false;
  for (int it = 0; it < 16; it++) {
    float mid = 0.5f * (lo + hi);
    int cnt = 0;
    #pragma unroll
    for (int j = 0; j < 64; j++) cnt += (sv[j] >= mid) ? 1 : 0;
    #pragma unroll
    for (int d = 1; d < 16; d <<= 1) cnt += __shfl_xor(cnt, d);
    bool win = (cnt >= 504 && cnt <= 520);
    if (win) Tsel = mid;
    done = done || win;
    if (cnt >= 512) lo = mid; else hi = mid;
    if (__all(done)) break;
  }
  float T = (Tsel > 0.f) ? Tsel : lo;

  // second-softmax coefficients: c = kept ? exp(w) : exp(0)=1
  float Z2 = 0.f;
  #pragma unroll
  for (int j = 0; j < 64; j++) {
    float c = (sv[j] >= T) ? __expf(sv[j] * invZ) : 1.0f;
    Z2 += c; sv[j] = c;
  }
  #pragma unroll
  for (int d = 1; d < 16; d <<= 1) Z2 += __shfl_xor(Z2, d);

  // write coefficients back to the exact locations this thread read (no barrier needed)
  u16* crow_p = scb + (size_t)row * 1028;
  #pragma unroll
  for (int u = 0; u < 16; u++) {
    h4 cv;
    #pragma unroll
    for (int e = 0; e < 4; e++) cv[e] = (_Float16)sv[4 * u + e];
    *(h4*)(crow_p + 4 * l16 + 64 * u) = cv;
  }
  if (l16 == 0) zinv[row] = 1.0f / Z2;
  __syncthreads();   // B2

  // ---- phase E: o = (c @ V) * zinv via f16 MFMA
  int n0 = w << 4;
  const u16* cb_row = scb + (size_t)l15 * 1028;
  f32x4 oacc = {};
  #pragma unroll
  for (int kt = 0; kt < 32; kt++) {
    uint2 c0 = *(const uint2*)(cb_row + kt * 32 + quad * 8);
    uint2 c1 = *(const uint2*)(cb_row + kt * 32 + quad * 8 + 4);
    h8 ca; ((uint2*)&ca)[0] = c0; ((uint2*)&ca)[1] = c1;
    h8 vv = *(const h8*)(vb + (size_t)(n0 + l15) * S_ + kt * 32 + quad * 8);
    oacc = __builtin_amdgcn_mfma_f32_16x16x32_f16(ca, vv, oacc, 0, 0, 0);
  }
  int b = bh >> 3, hh = bh & 7;
  #pragma unroll
  for (int r = 0; r < 4; r++) {
    int rr = quad * 4 + r;
    float o = oacc[r] * zinv[rr];
    attn[((size_t)b * S_ + r0 + rr) * D_ + hh * DH_ + n0 + l15] = f2bf(o);
  }
}

// ---------------- RMS norm over D per row: fp32 in, bf16 out ----------------
__global__ __launch_bounds__(128) void rms_kernel(const float* __restrict__ in,
                                                  const float* __restrict__ w,
                                                  u16* __restrict__ out) {
  int row = blockIdx.x;
  int tid = threadIdx.x;
  const float* r = in + (size_t)row * D_;
  float v0 = r[tid], v1 = r[tid + 128], v2 = r[tid + 256], v3 = r[tid + 384];
  float s = v0 * v0 + v1 * v1 + v2 * v2 + v3 * v3;
  #pragma unroll
  for (int d = 1; d < 64; d <<= 1) s += __shfl_xor(s, d);
  __shared__ float red[2];
  if ((tid & 63) == 0) red[tid >> 6] = s;
  __syncthreads();
  s = red[0] + red[1];
  float rs = rsqrtf(s * (1.0f / 512.0f) + 1e-6f);
  out[(size_t)row * D_ + tid      ] = f2bf(v0 * rs * w[tid      ]);
  out[(size_t)row * D_ + tid + 128] = f2bf(v1 * rs * w[tid + 128]);
  out[(size_t)row * D_ + tid + 256] = f2bf(v2 * rs * w[tid + 256]);
  out[(size_t)row * D_ + tid + 384] = f2bf(v3 * rs * w[tid + 384]);
}

// ---------------- silu(a)*b (bf16 in/out) ----------------
__global__ __launch_bounds__(256) void silu_mul_kernel(const u16* __restrict__ ab,
                                                       u16* __restrict__ g) {
  size_t i = ((size_t)blockIdx.x * 256 + threadIdx.x) * 8;
  size_t m = i / INNER_, j = i % INNER_;
  const u16* pa = ab + m * (2 * INNER_) + j;
  uint4 av = *(const uint4*)pa;
  uint4 bv = *(const uint4*)(pa + INNER_);
  unsigned int aa[4] = {av.x, av.y, av.z, av.w};
  unsigned int bb[4] = {bv.x, bv.y, bv.z, bv.w};
  unsigned int rr[4];
  #pragma unroll
  for (int t = 0; t < 4; t++) {
    float a0 = bf2f((u16)(aa[t] & 0xFFFF)), a1 = bf2f((u16)(aa[t] >> 16));
    float b0 = bf2f((u16)(bb[t] & 0xFFFF)), b1 = bf2f((u16)(bb[t] >> 16));
    float c0 = a0 / (1.f + __expf(-a0)) * b0;
    float c1 = a1 / (1.f + __expf(-a1)) * b1;
    rr[t] = (unsigned int)f2bf(c0) | ((unsigned int)f2bf(c1) << 16);
  }
  uint4 o; o.x = rr[0]; o.y = rr[1]; o.z = rr[2]; o.w = rr[3];
  *(uint4*)(g + m * INNER_ + j) = o;
}

// ---------------- instance norm: one-pass stats (no atomics), then apply ----------------
__global__ __launch_bounds__(256) void inorm_stats(const float* __restrict__ y,
                                                   float* __restrict__ stats) {
  int b = blockIdx.x, dc = blockIdx.y;
  int dl = threadIdx.x & 63, sl = threadIdx.x >> 6;
  int d = dc * 64 + dl;
  const float* yb = y + (size_t)b * S_ * D_ + d;
  float s1 = 0.f, s2 = 0.f;
  for (int i = 0; i < 256; i++) {
    int s = sl * 256 + i;
    float v = yb[(size_t)s * D_];
    s1 += v; s2 += v * v;
  }
  __shared__ float r1[256], r2[256];
  r1[threadIdx.x] = s1; r2[threadIdx.x] = s2;
  __syncthreads();
  if (sl == 0) {
    s1 = r1[dl] + r1[dl + 64] + r1[dl + 128] + r1[dl + 192];
    s2 = r2[dl] + r2[dl + 64] + r2[dl + 128] + r2[dl + 192];
    stats[((size_t)b * D_ + d) * 2]     = s1;
    stats[((size_t)b * D_ + d) * 2 + 1] = s2;
  }
}

__global__ __launch_bounds__(256) void inorm_apply(const float* __restrict__ y,
                                                   const float* __restrict__ stats,
                                                   const float* __restrict__ w,
                                                   const float* __restrict__ bias,
                                                   float* __restrict__ out) {
  int row = blockIdx.x;
  int b = row >> 10;
  int tid = threadIdx.x;
  #pragma unroll
  for (int i = 0; i < 2; i++) {
    int d = tid + i * 256;
    float m  = stats[((size_t)b * D_ + d) * 2]     * (1.f / 1024.f);
    float v2 = stats[((size_t)b * D_ + d) * 2 + 1] * (1.f / 1024.f);
    float rs = rsqrtf(v2 - m * m + 1e-5f);
    float v = y[(size_t)row * D_ + d];
    out[(size_t)row * D_ + d] = (v - m) * rs * w[d] + bias[d];
  }
}

// ---------------- launch ----------------
extern "C" void kernel_launch(void* const* d_in, const int* in_sizes, int n_in,
                              void* d_out, int out_size, void* d_ws, size_t ws_size,
                              hipStream_t stream) {
  const float* x    = (const float*)d_in[0];
  const float* Wq   = (const float*)d_in[1];
  const float* bq   = (const float*)d_in[2];
  const float* Wkv  = (const float*)d_in[3];
  const float* bkv  = (const float*)d_in[4];
  const float* Wo   = (const float*)d_in[5];
  const float* bo   = (const float*)d_in[6];
  const float* rmsw = (const float*)d_in[7];
  const float* l1   = (const float*)d_in[8];
  const float* l2   = (const float*)d_in[9];
  const float* l3   = (const float*)d_in[10];
  const float* inw  = (const float*)d_in[11];
  const float* inb  = (const float*)d_in[12];
  float* out = (float*)d_out;

  char* ws = (char*)d_ws;
  size_t off = 0;
  auto alloc = [&](size_t n) { char* p = ws + off; off += (n + 255) & ~(size_t)255; return p; };
  u16*  xb   = (u16*) alloc((size_t)M_ * D_ * 2);
  u16*  Wt1  = (u16*) alloc((size_t)1536 * 512 * 2);
  u16*  Wot  = (u16*) alloc((size_t)512 * 512 * 2);
  u16*  W12t = (u16*) alloc((size_t)3072 * 512 * 2);
  u16*  l3t  = (u16*) alloc((size_t)512 * 1536 * 2);
  u16*  qb   = (u16*) alloc((size_t)M_ * D_ * 2);      // f16 [B,H,S,DH]
  u16*  kb   = (u16*) alloc((size_t)M_ * D_ * 2);      // f16 [B,H,S,DH]
  u16*  vtb  = (u16*) alloc((size_t)M_ * D_ * 2);      // f16 [B,H,DH,S]
  u16*  attn = (u16*) alloc((size_t)M_ * D_ * 2);      // bf16 [B,S,D]
  float* tmpF = (float*)alloc((size_t)M_ * D_ * 4);
  u16*  hhat = (u16*) alloc((size_t)M_ * D_ * 2);
  u16*  ab   = (u16*) alloc((size_t)M_ * 3072 * 2);
  u16*  g    = (u16*) alloc((size_t)M_ * INNER_ * 2);
  float* stats = (float*)alloc((size_t)B_ * D_ * 2 * 4);

  transpose_all<<<832, 256, 0, stream>>>(Wq, Wkv, Wo, l1, l2, l3, Wt1, Wot, W12t, l3t);
  f2b_kernel<<<2048, 256, 0, stream>>>(x, xb);

  gemm_bt<1><<<dim3(12, 32), 256, 0, stream>>>(xb, Wt1, M_, 1536, 512,
      bq, bkv, nullptr, qb, kb, vtb);

  attn_kernel<<<2048, 256, 0, stream>>>(qb, kb, vtb, attn);

  gemm64<2><<<dim3(8, 64), 256, 0, stream>>>(attn, Wot, M_, 512, 512,
      bo, x, nullptr, tmpF);

  rms_kernel<<<4096, 128, 0, stream>>>(tmpF, rmsw, hhat);

  gemm_bt<3><<<dim3(24, 32), 256, 0, stream>>>(hhat, W12t, M_, 3072, 512,
      nullptr, nullptr, ab, nullptr, nullptr, nullptr);

  silu_mul_kernel<<<3072, 256, 0, stream>>>(ab, g);

  gemm64<4><<<dim3(8, 64), 256, 0, stream>>>(g, l3t, M_, 512, 1536,
      nullptr, nullptr, hhat, tmpF);

  inorm_stats<<<dim3(4, 8), 256, 0, stream>>>(tmpF, stats);
  inorm_apply<<<4096, 256, 0, stream>>>(tmpF, stats, inw, inb, out);
}